// Round 6
// baseline (615.892 us; speedup 1.0000x reference)
//
#include <hip/hip_runtime.h>
#include <cstdint>

typedef _Float16 half8 __attribute__((ext_vector_type(8)));
typedef __attribute__((ext_vector_type(4))) float floatx4;

#define TSEQ 256
#define TDEC 180
#define NIN  6
#define GROWS 8   // 8 rows/block -> 512 blocks = 2 independent blocks/CU to fill latency bubbles
#define NBLK (4096 / GROWS)
#define NSL 4     // state buffer depth: h(j) lives in slot (j+1)&3
#define RS0 104   // s0 row stride (halfs): cols 0..63 h0, 64..95 x|0, 96..103 pad
#define RS1 72    // s1 row stride
#define L2E 1.4426950408889634f

__device__ __forceinline__ floatx4 mfma16(half8 a, half8 b, floatx4 c) {
  return __builtin_amdgcn_mfma_f32_16x16x32_f16(a, b, c, 0, 0, 0);
}

// pre-scaled transcendentals: inputs already carry log2e (sigm) / 2*log2e (tanh)
// Shared-rcp sigmoid pair: one rcp serves both r and z gates (trans 6->5 per elem).
__device__ __forceinline__ void sigm2pair(float vr, float vz, float& gr, float& gz) {
  const float d1 = 1.0f + __builtin_amdgcn_exp2f(-vr);
  const float d2 = 1.0f + __builtin_amdgcn_exp2f(-vz);
  const float rp = __builtin_amdgcn_rcpf(d1 * d2);
  gr = rp * d2;
  gz = rp * d1;
}
__device__ __forceinline__ float tanh2(float v) {
  return fmaf(2.0f, __builtin_amdgcn_rcpf(1.0f + __builtin_amdgcn_exp2f(-v)), -1.0f);
}

__device__ __forceinline__ half8 ldh8(const _Float16* p) { return *(const half8*)p; }

#define PASS2_I3(F0, F1, r, z, g, W, QR, QZ, QG) do {                   \
  r = mfma16(F0, W[0][0], QR); z = mfma16(F0, W[1][0], QZ); g = mfma16(F0, W[2][0], QG); \
  r = mfma16(F1, W[0][1], r);  z = mfma16(F1, W[1][1], z);  g = mfma16(F1, W[2][1], g);  \
} while (0)

#define PASS2_A2I1(F0, F1, r, z, g, W, QG) do {                         \
  r = mfma16(F0, W[0][0], r); z = mfma16(F0, W[1][0], z); g = mfma16(F0, W[2][0], QG); \
  r = mfma16(F1, W[0][1], r); z = mfma16(F1, W[1][1], z); g = mfma16(F1, W[2][1], g);  \
} while (0)

#define PASS1_A2I1(F0, r, z, g, W, QG) do {                             \
  r = mfma16(F0, W[0][0], r); z = mfma16(F0, W[1][0], z); g = mfma16(F0, W[2][0], QG); \
} while (0)

// Lockstep barrier: drain this wave's LDS ops (writes become visible), then
// raw s_barrier. Deliberately NO vmcnt drain so the x global prefetch loads
// stay in flight across barriers. Memory clobbers pin LDS ops on each side.
#define SYNC() do {                                         \
  asm volatile("s_waitcnt lgkmcnt(0)" ::: "memory");        \
  __builtin_amdgcn_s_barrier();                             \
  asm volatile("" ::: "memory");                            \
} while (0)

// NOTE: second arg = min blocks/CU hint. (512,4) forced VGPR->64 and spilled the
// register-resident weights (R5: WRITE_SIZE 2880->79872 KB). (512,2) keeps the
// natural ~108 VGPR <= 128, which the HW co-schedules as 2 blocks/CU anyway.
__global__ void __launch_bounds__(512, 2)
gru_persist(const float* __restrict__ x,
            const float* __restrict__ eWih0, const float* __restrict__ eWhh0,
            const float* __restrict__ ebih0, const float* __restrict__ ebhh0,
            const float* __restrict__ eWih1, const float* __restrict__ eWhh1,
            const float* __restrict__ ebih1, const float* __restrict__ ebhh1,
            const float* __restrict__ dWih0, const float* __restrict__ dWhh0,
            const float* __restrict__ dbih0, const float* __restrict__ dbhh0,
            const float* __restrict__ dWih1, const float* __restrict__ dWhh1,
            const float* __restrict__ dbih1, const float* __restrict__ dbhh1,
            const float* __restrict__ outW, const float* __restrict__ outB,
            float* __restrict__ out)
{
  __shared__ __align__(16) _Float16 s0[NSL][16][RS0];
  __shared__ __align__(16) _Float16 s1[NSL][16][RS1];

  const int tid  = threadIdx.x;
  const bool isA = tid < 256;          // A = layer0 waves, B = layer1 waves
  const int wvL  = (tid >> 6) & 3;
  const int lane = tid & 63;
  const int c    = lane & 15;
  const int q    = lane >> 4;
  const int u    = wvL * 16 + c;
  const long base = (long)blockIdx.x * GROWS;

  for (int i = tid; i < NSL * 16 * RS0; i += 512) ((uint16_t*)s0)[i] = 0;
  for (int i = tid; i < NSL * 16 * RS1; i += 512) ((uint16_t*)s1)[i] = 0;
  if (tid < GROWS * NIN) {  // x(0) -> s0[0]
    int m = tid / 6, i2 = tid - m * 6;
    s0[0][m][64 + i2] = (_Float16)x[(base + m) * (TSEQ * NIN) + i2];
  }

  // encoder + decoder weights ALL register-resident from the start (no mid-kernel loads)
  half8 W1[3][2], W2[3][2];    // encoder: A: Whh0 / [Wih0|0] | B: Wih1 / Whh1
  half8 W1d[3][2], W2d[3][2];  // decoder: A: Whh0d / rank-1 fold | B: Wih1d / Whh1d
  float hr[4] = {0, 0, 0, 0};
  const float SC[3] = {L2E, L2E, 2.0f * L2E};   // r, z, n row scales (fold exp2 args)

  auto loadW64 = [&](const float* W, half8 (&D)[3][2]) {
    #pragma unroll
    for (int s = 0; s < 3; s++) {
      const int n = (s * 4 + wvL) * 16 + c;
      #pragma unroll
      for (int kt = 0; kt < 2; kt++) {
        const int k0 = kt * 32 + q * 8;
        #pragma unroll
        for (int j = 0; j < 8; j++) D[s][kt][j] = (_Float16)(SC[s] * W[n * 64 + k0 + j]);
      }
    }
  };

  const float ob = outB[0];
  float cR, cZ, c3, c4;          // encoder consts
  float dR, dZ, d3, d4;          // decoder steady consts
  float bR0 = 0, bZ0 = 0, b30 = 0, b40 = 0;   // A decoder first-step consts
  float wk[2][8];                // B: head weights
  if (isA) {
    loadW64(eWhh0, W1);
    #pragma unroll
    for (int s = 0; s < 3; s++) {
      const int n = (s * 4 + wvL) * 16 + c;
      #pragma unroll
      for (int kt = 0; kt < 2; kt++)
        #pragma unroll
        for (int j = 0; j < 8; j++) {
          float v = (kt == 0 && q == 0 && j < NIN) ? SC[s] * eWih0[n * NIN + j] : 0.0f;
          W2[s][kt][j] = (_Float16)v;
        }
    }
    loadW64(dWhh0, W1d);
    #pragma unroll
    for (int s = 0; s < 3; s++) {   // W2d = rank-1 head fold: SC[s] * dWih0[n] * outW[k]
      const int n = (s * 4 + wvL) * 16 + c;
      const float wd = SC[s] * dWih0[n];
      #pragma unroll
      for (int kt = 0; kt < 2; kt++) {
        const int k0 = kt * 32 + q * 8;
        #pragma unroll
        for (int j = 0; j < 8; j++) W2d[s][kt][j] = (_Float16)(wd * outW[k0 + j]);
      }
    }
    cR = L2E * (ebih0[u] + ebhh0[u]);
    cZ = L2E * (ebih0[64 + u] + ebhh0[64 + u]);
    c3 = 2.0f * L2E * ebhh0[128 + u];   // gh const
    c4 = 2.0f * L2E * ebih0[128 + u];   // gi const
    bR0 = L2E * (dbih0[u] + dbhh0[u]);
    bZ0 = L2E * (dbih0[64 + u] + dbhh0[64 + u]);
    b30 = 2.0f * L2E * dbhh0[128 + u];
    b40 = 2.0f * L2E * dbih0[128 + u];
    dR = bR0 + L2E * (dWih0[u] * ob);
    dZ = bZ0 + L2E * (dWih0[64 + u] * ob);
    d3 = b30;
    d4 = b40 + 2.0f * L2E * (dWih0[128 + u] * ob);
  } else {
    loadW64(eWih1, W1); loadW64(eWhh1, W2);
    loadW64(dWih1, W1d); loadW64(dWhh1, W2d);
    cR = L2E * (ebih1[u] + ebhh1[u]);
    cZ = L2E * (ebih1[64 + u] + ebhh1[64 + u]);
    c3 = 2.0f * L2E * ebih1[128 + u];   // gi const
    c4 = 2.0f * L2E * ebhh1[128 + u];   // gh const
    dR = L2E * (dbih1[u] + dbhh1[u]);
    dZ = L2E * (dbih1[64 + u] + dbhh1[64 + u]);
    d3 = 2.0f * L2E * dbih1[128 + u];
    d4 = 2.0f * L2E * dbhh1[128 + u];
    #pragma unroll
    for (int kt = 0; kt < 2; kt++)
      #pragma unroll
      for (int j = 0; j < 8; j++) wk[kt][j] = outW[kt * 32 + q * 8 + j];
  }
  __syncthreads();   // everything after runs on the lockstep barrier schedule

  // Barrier schedule (both sides execute exactly 616 SYNCs):
  //   encoder: 256 iters (1 SYNC each) + 1 tail iter (A: decoder peel, B: enc step 255)
  //   decoder: B(0) window (1 SYNC), then 179 iters x 2 SYNCs; A adds 1 trailing SYNC.
  if (isA) {
    floatx4 QR = {cR, cR, cR, cR}, QZ = {cZ, cZ, cZ, cZ};
    floatx4 Q3 = {c3, c3, c3, c3}, Q4 = {c4, c4, c4, c4};
    // ---- x prefetch, spread over ALL 4 A-waves (lanes 0..11, 1 slot each, depth 2)
    // 48 slots = 8 rows x 6 features; no single wave straggles at the barrier.
    const bool doX = (lane < 12);
    const float *px0 = nullptr;
    int xo0 = 0;
    float xa0 = 0.f, xb0 = 0.f;   // (xa=next-to-write, xb=following)
    if (doX) {
      int s_ = wvL * 12 + lane;                 // 48 slots
      int m0 = s_ / 6, i0 = s_ - m0 * 6;
      px0 = x + (base + m0) * (TSEQ * NIN) + i0;
      xo0 = m0 * RS0 + 64 + i0;
      xa0 = px0[NIN];       // x(1)
      xb0 = px0[2 * NIN];   // x(2)
    }
    // ================= encoder: iteration k computes h0_out(k) =================
    for (int k = 0; k < TSEQ; k += 4) {
      #pragma unroll
      for (int h4 = 0; h4 < 4; h4++) {
        const int i_ = k + h4, p = h4, pn = (h4 + 1) & 3;
        const half8 a0 = ldh8(&s0[p][c][q * 8]);
        const half8 a1 = ldh8(&s0[p][c][32 + q * 8]);
        const half8 xf = ldh8(&s0[p][c][64 + q * 8]);
        floatx4 aR, aZ, a3, a4;
        PASS2_I3(a0, a1, aR, aZ, a3, W1, QR, QZ, Q3);  // Whh0.h0 -> gh
        PASS1_A2I1(xf, aR, aZ, a4, W2, Q4);            // Wih0.x  -> gi
        if (doX && i_ + 1 < TSEQ) {
          ((_Float16*)s0[pn])[xo0] = (_Float16)xa0;
          xa0 = xb0;
          if (i_ + 3 < TSEQ) xb0 = px0[(i_ + 3) * NIN];
        }
        #pragma unroll
        for (int r4 = 0; r4 < 4; r4++) {
          float gr, gz;
          sigm2pair(aR[r4], aZ[r4], gr, gz);
          const float nn = tanh2(a4[r4] + gr * a3[r4]);
          const float hn = nn + gz * (hr[r4] - nn);
          hr[r4] = hn;
          s0[pn][q * 4 + r4][u] = (_Float16)hn;
        }
        SYNC();
      }
    }
    // ---- tail iteration (k=TSEQ): decoder peel A(0), prev = 0 -> base biases ----
    // s0[0] = h0_out(255); writes h0_dec(0) -> s0[1]. Overlaps B's enc step 255.
    {
      const half8 a0 = ldh8(&s0[0][c][q * 8]);
      const half8 a1 = ldh8(&s0[0][c][32 + q * 8]);
      const floatx4 TR = {bR0, bR0, bR0, bR0}, TZ = {bZ0, bZ0, bZ0, bZ0};
      const floatx4 T3 = {b30, b30, b30, b30};
      floatx4 aR, aZ, a3;
      floatx4 a4 = {b40, b40, b40, b40};
      PASS2_I3(a0, a1, aR, aZ, a3, W1d, TR, TZ, T3);
      #pragma unroll
      for (int r4 = 0; r4 < 4; r4++) {
        float gr, gz;
        sigm2pair(aR[r4], aZ[r4], gr, gz);
        const float nn = tanh2(a4[r4] + gr * a3[r4]);
        const float hn = nn + gz * (hr[r4] - nn);
        hr[r4] = hn;
        s0[1][q * 4 + r4][u] = (_Float16)hn;
      }
      SYNC();   // bar0: h0_dec(0) visible; B(0) runs in the next window
    }
    // ---- decoder steady: d = 1..179 (i_ = TSEQ+d), 2 barriers per step ----
    QR = (floatx4){dR, dR, dR, dR}; QZ = (floatx4){dZ, dZ, dZ, dZ};
    Q3 = (floatx4){d3, d3, d3, d3}; Q4 = (floatx4){d4, d4, d4, d4};
    for (int i_ = TSEQ + 1; i_ < TSEQ + TDEC; i_++) {
      const int p = i_ & 3, pn = (i_ + 1) & 3;
      // prepass (overlaps B finishing d-1): Whh0d.h0_dec(d-1)
      const half8 a0 = ldh8(&s0[p][c][q * 8]);
      const half8 a1 = ldh8(&s0[p][c][32 + q * 8]);
      floatx4 aR, aZ, a3, a4;
      PASS2_I3(a0, a1, aR, aZ, a3, W1d, QR, QZ, Q3);
      SYNC();                                          // B(d-1) done -> s1[p] = h1(d-1)
      const half8 b0 = ldh8(&s1[p][c][q * 8]);         // rank-1 head fold: W'.h1(d-1)
      const half8 b1 = ldh8(&s1[p][c][32 + q * 8]);
      PASS2_A2I1(b0, b1, aR, aZ, a4, W2d, Q4);
      #pragma unroll
      for (int r4 = 0; r4 < 4; r4++) {
        float gr, gz;
        sigm2pair(aR[r4], aZ[r4], gr, gz);
        const float nn = tanh2(a4[r4] + gr * a3[r4]);
        const float hn = nn + gz * (hr[r4] - nn);
        hr[r4] = hn;
        s0[pn][q * 4 + r4][u] = (_Float16)hn;
      }
      SYNC();                                          // A(d) done -> s0[pn]
    }
    SYNC();   // match B's barrier after its last finish (B(179))
  } else {
    // =========================== group B: layer 1 ===========================
    floatx4 QR = {cR, cR, cR, cR}, QZ = {cZ, cZ, cZ, cZ};
    floatx4 Q3 = {c3, c3, c3, c3}, Q4 = {c4, c4, c4, c4};
    // ============ encoder: iteration kk computes h1_out(kk-1), kk>=1 ============
    for (int k = 0; k < TSEQ; k += 4) {
      #pragma unroll
      for (int h4 = 0; h4 < 4; h4++) {
        const int kk = k + h4;
        if (kk > 0) {
          const int p = (h4 + 3) & 3, pn = h4;         // read s1[(kk-1)&3], s0[kk&3]
          const half8 f0 = ldh8(&s1[p][c][q * 8]);
          const half8 f1 = ldh8(&s1[p][c][32 + q * 8]);
          floatx4 aR, aZ, a3, a4;
          PASS2_I3(f0, f1, aR, aZ, a4, W2, QR, QZ, Q4);  // Whh1.h1 -> gh
          const half8 g0 = ldh8(&s0[pn][c][q * 8]);      // h0_out(kk-1), from prev window
          const half8 g1 = ldh8(&s0[pn][c][32 + q * 8]);
          PASS2_A2I1(g0, g1, aR, aZ, a3, W1, Q3);        // Wih1.h0 -> gi
          #pragma unroll
          for (int r4 = 0; r4 < 4; r4++) {
            float gr, gz;
            sigm2pair(aR[r4], aZ[r4], gr, gz);
            const float nn = tanh2(a3[r4] + gr * a4[r4]);
            const float hn = nn + gz * (hr[r4] - nn);
            hr[r4] = hn;
            s1[pn][q * 4 + r4][u] = (_Float16)hn;
          }
        }
        SYNC();
      }
    }
    // ---- tail iteration (kk=TSEQ): encoder step i_=255: s1[3], s0[0] -> s1[0] ----
    {
      const half8 f0 = ldh8(&s1[3][c][q * 8]);
      const half8 f1 = ldh8(&s1[3][c][32 + q * 8]);
      floatx4 aR, aZ, a3, a4;
      PASS2_I3(f0, f1, aR, aZ, a4, W2, QR, QZ, Q4);
      const half8 g0 = ldh8(&s0[0][c][q * 8]);
      const half8 g1 = ldh8(&s0[0][c][32 + q * 8]);
      PASS2_A2I1(g0, g1, aR, aZ, a3, W1, Q3);
      #pragma unroll
      for (int r4 = 0; r4 < 4; r4++) {
        float gr, gz;
        sigm2pair(aR[r4], aZ[r4], gr, gz);
        const float nn = tanh2(a3[r4] + gr * a4[r4]);
        const float hn = nn + gz * (hr[r4] - nn);
        hr[r4] = hn;
        s1[0][q * 4 + r4][u] = (_Float16)hn;
      }
      SYNC();   // bar0
    }
    QR = (floatx4){dR, dR, dR, dR}; QZ = (floatx4){dZ, dZ, dZ, dZ};
    Q3 = (floatx4){d3, d3, d3, d3}; Q4 = (floatx4){d4, d4, d4, d4};
    // ---- B(0): s1[0] = h1_out(255), s0[1] = h0_dec(0) -> s1[1] = h1_dec(0) ----
    {
      const half8 f0 = ldh8(&s1[0][c][q * 8]);
      const half8 f1 = ldh8(&s1[0][c][32 + q * 8]);
      floatx4 aR, aZ, a3, a4;
      PASS2_I3(f0, f1, aR, aZ, a4, W2d, QR, QZ, Q4);
      const half8 g0 = ldh8(&s0[1][c][q * 8]);
      const half8 g1 = ldh8(&s0[1][c][32 + q * 8]);
      PASS2_A2I1(g0, g1, aR, aZ, a3, W1d, Q3);
      #pragma unroll
      for (int r4 = 0; r4 < 4; r4++) {
        float gr, gz;
        sigm2pair(aR[r4], aZ[r4], gr, gz);
        const float nn = tanh2(a3[r4] + gr * a4[r4]);
        const float hn = nn + gz * (hr[r4] - nn);
        hr[r4] = hn;
        s1[1][q * 4 + r4][u] = (_Float16)hn;
      }
      SYNC();   // bar1: h1_dec(0) visible
    }
    // ---- decoder steady: d = 1..179 (i_ = TSEQ+d), 2 barriers per step ----
    for (int i_ = TSEQ + 1; i_ < TSEQ + TDEC; i_++) {
      const int p = i_ & 3, pn = (i_ + 1) & 3;
      // prepass (overlaps A finishing d): Whh1d.h1_dec(d-1), + head cv(d-1)
      const half8 f0 = ldh8(&s1[p][c][q * 8]);
      const half8 f1 = ldh8(&s1[p][c][32 + q * 8]);
      floatx4 aR, aZ, a3, a4;
      PASS2_I3(f0, f1, aR, aZ, a4, W2d, QR, QZ, Q4);   // Whh1.h1 -> gh
      if (wvL == 0) {   // head: cv(d-1) from h1_dec(d-1) fragments (off critical path)
        float cv = 0.0f;
        #pragma unroll
        for (int j = 0; j < 8; j++) {
          cv = fmaf((float)f0[j], wk[0][j], cv);
          cv = fmaf((float)f1[j], wk[1][j], cv);
        }
        cv += __shfl_xor(cv, 16);
        cv += __shfl_xor(cv, 32);
        if (lane < GROWS) out[(base + lane) * TDEC + (i_ - TSEQ - 1)] = cv + ob;
      }
      SYNC();                                          // A(d) done -> s0[pn] = h0_dec(d)
      const half8 g0 = ldh8(&s0[pn][c][q * 8]);
      const half8 g1 = ldh8(&s0[pn][c][32 + q * 8]);
      PASS2_A2I1(g0, g1, aR, aZ, a3, W1d, Q3);         // Wih1.h0 -> gi
      #pragma unroll
      for (int r4 = 0; r4 < 4; r4++) {
        float gr, gz;
        sigm2pair(aR[r4], aZ[r4], gr, gz);
        const float nn = tanh2(a3[r4] + gr * a4[r4]);
        const float hn = nn + gz * (hr[r4] - nn);
        hr[r4] = hn;
        s1[pn][q * 4 + r4][u] = (_Float16)hn;
      }
      SYNC();                                          // B(d) done -> s1[pn]
    }
    // final head value: cv(179) from h1_dec(179) in s1[(436)&3 = 0]
    if (wvL == 0) {
      const half8 f0 = ldh8(&s1[0][c][q * 8]);
      const half8 f1 = ldh8(&s1[0][c][32 + q * 8]);
      float cv = 0.0f;
      #pragma unroll
      for (int j = 0; j < 8; j++) {
        cv = fmaf((float)f0[j], wk[0][j], cv);
        cv = fmaf((float)f1[j], wk[1][j], cv);
      }
      cv += __shfl_xor(cv, 16);
      cv += __shfl_xor(cv, 32);
      if (lane < GROWS) out[(base + lane) * TDEC + (TDEC - 1)] = cv + ob;
    }
  }
}

extern "C" void kernel_launch(void* const* d_in, const int* in_sizes, int n_in,
                              void* d_out, int out_size, void* d_ws, size_t ws_size,
                              hipStream_t stream) {
  (void)in_sizes; (void)n_in; (void)d_ws; (void)ws_size; (void)out_size;
  const float* x     = (const float*)d_in[0];
  const float* eWih0 = (const float*)d_in[1];
  const float* eWhh0 = (const float*)d_in[2];
  const float* ebih0 = (const float*)d_in[3];
  const float* ebhh0 = (const float*)d_in[4];
  const float* eWih1 = (const float*)d_in[5];
  const float* eWhh1 = (const float*)d_in[6];
  const float* ebih1 = (const float*)d_in[7];
  const float* ebhh1 = (const float*)d_in[8];
  const float* dWih0 = (const float*)d_in[9];
  const float* dWhh0 = (const float*)d_in[10];
  const float* dbih0 = (const float*)d_in[11];
  const float* dbhh0 = (const float*)d_in[12];
  const float* dWih1 = (const float*)d_in[13];
  const float* dWhh1 = (const float*)d_in[14];
  const float* dbih1 = (const float*)d_in[15];
  const float* dbhh1 = (const float*)d_in[16];
  const float* outW  = (const float*)d_in[17];
  const float* outB  = (const float*)d_in[18];
  hipLaunchKernelGGL(gru_persist, dim3(NBLK), dim3(512), 0, stream,
                     x, eWih0, eWhh0, ebih0, ebhh0, eWih1, eWhh1, ebih1, ebhh1,
                     dWih0, dWhh0, dbih0, dbhh0, dWih1, dWhh1, dbih1, dbhh1,
                     outW, outB, (float*)d_out);
}

// Round 7
// 534.464 us; speedup vs baseline: 1.1524x; 1.1524x over previous
//
#include <hip/hip_runtime.h>
#include <cstdint>

typedef _Float16 half8 __attribute__((ext_vector_type(8)));
typedef __attribute__((ext_vector_type(4))) float floatx4;

#define TSEQ 256
#define TDEC 180
#define NIN  6
#define GROWS 8   // 8 rows/block -> 512 blocks; with <=128 regs/wave -> 2 blocks/CU
#define NBLK (4096 / GROWS)
#define NSL 4     // state buffer depth: h(j) lives in slot (j+1)&3
#define RS0 104   // s0 row stride (halfs): cols 0..63 h0, 64..95 x|0, 96..103 pad
#define RS1 72    // s1 row stride
#define L2E 1.4426950408889634f

__device__ __forceinline__ floatx4 mfma16(half8 a, half8 b, floatx4 c) {
  return __builtin_amdgcn_mfma_f32_16x16x32_f16(a, b, c, 0, 0, 0);
}

// pre-scaled transcendentals: inputs already carry log2e (sigm) / 2*log2e (tanh)
// Shared-rcp sigmoid pair: one rcp serves both r and z gates.
__device__ __forceinline__ void sigm2pair(float vr, float vz, float& gr, float& gz) {
  const float d1 = 1.0f + __builtin_amdgcn_exp2f(-vr);
  const float d2 = 1.0f + __builtin_amdgcn_exp2f(-vz);
  const float rp = __builtin_amdgcn_rcpf(d1 * d2);
  gr = rp * d2;
  gz = rp * d1;
}
__device__ __forceinline__ float tanh2(float v) {
  return fmaf(2.0f, __builtin_amdgcn_rcpf(1.0f + __builtin_amdgcn_exp2f(-v)), -1.0f);
}

__device__ __forceinline__ half8 ldh8(const _Float16* p) { return *(const half8*)p; }

#define PASS2_I3(F0, F1, r, z, g, W, QR, QZ, QG) do {                   \
  r = mfma16(F0, W[0][0], QR); z = mfma16(F0, W[1][0], QZ); g = mfma16(F0, W[2][0], QG); \
  r = mfma16(F1, W[0][1], r);  z = mfma16(F1, W[1][1], z);  g = mfma16(F1, W[2][1], g);  \
} while (0)

#define PASS2_A2I1(F0, F1, r, z, g, W, QG) do {                         \
  r = mfma16(F0, W[0][0], r); z = mfma16(F0, W[1][0], z); g = mfma16(F0, W[2][0], QG); \
  r = mfma16(F1, W[0][1], r); z = mfma16(F1, W[1][1], z); g = mfma16(F1, W[2][1], g);  \
} while (0)

// A-encoder x-pass: only the first K-half is nonzero (x has 6 features) -> 1-D W.
#define PASS1_I1(F0, r, z, g, W3, QG) do {                              \
  r = mfma16(F0, W3[0], r); z = mfma16(F0, W3[1], z); g = mfma16(F0, W3[2], QG); \
} while (0)

// Lockstep barrier: drain this wave's LDS ops (writes become visible), then
// raw s_barrier. Deliberately NO vmcnt drain so global prefetch loads stay in
// flight across barriers. Memory clobbers pin LDS ops on each side (and fence
// the transition-time global weight loads from being hoisted into the encoder).
#define SYNC() do {                                         \
  asm volatile("s_waitcnt lgkmcnt(0)" ::: "memory");        \
  __builtin_amdgcn_s_barrier();                             \
  asm volatile("" ::: "memory");                            \
} while (0)

// (512,4): 4 waves/EU minimum -> 128-reg budget. Feasible now because decoder
// weights are loaded at the transition (peak live = one phase's weights only).
// R5's spill disaster was this bound with ALL weights live; R6 showed ~136 total
// regs -> 3 waves/SIMD -> no block co-residency.
__global__ void __launch_bounds__(512, 4)
gru_persist(const float* __restrict__ x,
            const float* __restrict__ eWih0, const float* __restrict__ eWhh0,
            const float* __restrict__ ebih0, const float* __restrict__ ebhh0,
            const float* __restrict__ eWih1, const float* __restrict__ eWhh1,
            const float* __restrict__ ebih1, const float* __restrict__ ebhh1,
            const float* __restrict__ dWih0, const float* __restrict__ dWhh0,
            const float* __restrict__ dbih0, const float* __restrict__ dbhh0,
            const float* __restrict__ dWih1, const float* __restrict__ dWhh1,
            const float* __restrict__ dbih1, const float* __restrict__ dbhh1,
            const float* __restrict__ outW, const float* __restrict__ outB,
            float* __restrict__ out)
{
  __shared__ __align__(16) _Float16 s0[NSL][16][RS0];
  __shared__ __align__(16) _Float16 s1[NSL][16][RS1];
  __shared__ __align__(16) float swk[64];   // head weights (B reads per step, off critical path)

  const int tid  = threadIdx.x;
  const bool isA = tid < 256;          // A = layer0 waves, B = layer1 waves
  const int wvL  = (tid >> 6) & 3;
  const int lane = tid & 63;
  const int c    = lane & 15;
  const int q    = lane >> 4;
  const int u    = wvL * 16 + c;
  const long base = (long)blockIdx.x * GROWS;

  for (int i = tid; i < NSL * 16 * RS0; i += 512) ((uint16_t*)s0)[i] = 0;
  for (int i = tid; i < NSL * 16 * RS1; i += 512) ((uint16_t*)s1)[i] = 0;
  if (tid < 64) swk[tid] = outW[tid];
  if (tid < GROWS * NIN) {  // x(0) -> s0[0]
    int m = tid / 6, i2 = tid - m * 6;
    s0[0][m][64 + i2] = (_Float16)x[(base + m) * (TSEQ * NIN) + i2];
  }

  // ---- encoder weights only (decoder weights loaded at the transition) ----
  half8 W1[3][2];   // A: Whh0 | B: Wih1
  half8 W2[3][2];   // B: Whh1 (A does not use)
  half8 W2e[3];     // A: Wih0 fold, first K-half only
  float hr[4] = {0, 0, 0, 0};
  const float SC[3] = {L2E, L2E, 2.0f * L2E};   // r, z, n row scales (fold exp2 args)

  auto loadW64 = [&](const float* W, half8 (&D)[3][2]) {
    #pragma unroll
    for (int s = 0; s < 3; s++) {
      const int n = (s * 4 + wvL) * 16 + c;
      #pragma unroll
      for (int kt = 0; kt < 2; kt++) {
        const int k0 = kt * 32 + q * 8;
        #pragma unroll
        for (int j = 0; j < 8; j++) D[s][kt][j] = (_Float16)(SC[s] * W[n * 64 + k0 + j]);
      }
    }
  };

  const float ob = outB[0];
  float cR, cZ, c3, c4;          // encoder consts
  if (isA) {
    loadW64(eWhh0, W1);
    #pragma unroll
    for (int s = 0; s < 3; s++) {
      const int n = (s * 4 + wvL) * 16 + c;
      #pragma unroll
      for (int j = 0; j < 8; j++) {
        float v = (q == 0 && j < NIN) ? SC[s] * eWih0[n * NIN + j] : 0.0f;
        W2e[s][j] = (_Float16)v;
      }
    }
    cR = L2E * (ebih0[u] + ebhh0[u]);
    cZ = L2E * (ebih0[64 + u] + ebhh0[64 + u]);
    c3 = 2.0f * L2E * ebhh0[128 + u];   // gh const
    c4 = 2.0f * L2E * ebih0[128 + u];   // gi const
  } else {
    loadW64(eWih1, W1); loadW64(eWhh1, W2);
    cR = L2E * (ebih1[u] + ebhh1[u]);
    cZ = L2E * (ebih1[64 + u] + ebhh1[64 + u]);
    c3 = 2.0f * L2E * ebih1[128 + u];   // gi const
    c4 = 2.0f * L2E * ebhh1[128 + u];   // gh const
  }
  __syncthreads();   // everything after runs on the lockstep barrier schedule

  // Barrier schedule (both sides execute exactly 616 SYNCs):
  //   encoder: 256 iters (1 SYNC each) + 1 tail iter (A: decoder peel, B: enc step 255)
  //   decoder: B(0) window (1 SYNC), then 179 iters x 2 SYNCs; A adds 1 trailing SYNC.
  if (isA) {
    floatx4 QR = {cR, cR, cR, cR}, QZ = {cZ, cZ, cZ, cZ};
    floatx4 Q3 = {c3, c3, c3, c3}, Q4 = {c4, c4, c4, c4};
    // ---- x prefetch, spread over ALL 4 A-waves (lanes 0..11, 1 slot each, depth 2)
    const bool doX = (lane < 12);
    const float *px0 = nullptr;
    int xo0 = 0;
    float xa0 = 0.f, xb0 = 0.f;   // (xa=next-to-write, xb=following)
    if (doX) {
      int s_ = wvL * 12 + lane;                 // 48 slots = 8 rows x 6 features
      int m0 = s_ / 6, i0 = s_ - m0 * 6;
      px0 = x + (base + m0) * (TSEQ * NIN) + i0;
      xo0 = m0 * RS0 + 64 + i0;
      xa0 = px0[NIN];       // x(1)
      xb0 = px0[2 * NIN];   // x(2)
    }
    // ================= encoder: iteration k computes h0_out(k) =================
    for (int k = 0; k < TSEQ; k += 4) {
      #pragma unroll
      for (int h4 = 0; h4 < 4; h4++) {
        const int i_ = k + h4, p = h4, pn = (h4 + 1) & 3;
        const half8 a0 = ldh8(&s0[p][c][q * 8]);
        const half8 a1 = ldh8(&s0[p][c][32 + q * 8]);
        const half8 xf = ldh8(&s0[p][c][64 + q * 8]);
        floatx4 aR, aZ, a3, a4;
        PASS2_I3(a0, a1, aR, aZ, a3, W1, QR, QZ, Q3);  // Whh0.h0 -> gh
        a4 = Q4;
        PASS1_I1(xf, aR, aZ, a4, W2e, Q4);             // Wih0.x  -> gi (K-half 0 only)
        if (doX && i_ + 1 < TSEQ) {
          ((_Float16*)s0[pn])[xo0] = (_Float16)xa0;
          xa0 = xb0;
          if (i_ + 3 < TSEQ) xb0 = px0[(i_ + 3) * NIN];
        }
        #pragma unroll
        for (int r4 = 0; r4 < 4; r4++) {
          float gr, gz;
          sigm2pair(aR[r4], aZ[r4], gr, gz);
          const float nn = tanh2(a4[r4] + gr * a3[r4]);
          const float hn = nn + gz * (hr[r4] - nn);
          hr[r4] = hn;
          s0[pn][q * 4 + r4][u] = (_Float16)hn;
        }
        SYNC();
      }
    }
    // ---- transition: load decoder weights + consts (once; L2-hit) ----
    half8 W1d[3][2], W2d[3][2];
    loadW64(dWhh0, W1d);
    #pragma unroll
    for (int s = 0; s < 3; s++) {   // W2d = rank-1 head fold: SC[s] * dWih0[n] * outW[k]
      const int n = (s * 4 + wvL) * 16 + c;
      const float wd = SC[s] * dWih0[n];
      #pragma unroll
      for (int kt = 0; kt < 2; kt++) {
        const int k0 = kt * 32 + q * 8;
        #pragma unroll
        for (int j = 0; j < 8; j++) W2d[s][kt][j] = (_Float16)(wd * outW[k0 + j]);
      }
    }
    const float bR0 = L2E * (dbih0[u] + dbhh0[u]);
    const float bZ0 = L2E * (dbih0[64 + u] + dbhh0[64 + u]);
    const float b30 = 2.0f * L2E * dbhh0[128 + u];
    const float b40 = 2.0f * L2E * dbih0[128 + u];
    const float dR = bR0 + L2E * (dWih0[u] * ob);
    const float dZ = bZ0 + L2E * (dWih0[64 + u] * ob);
    const float d3 = b30;
    const float d4 = b40 + 2.0f * L2E * (dWih0[128 + u] * ob);
    // ---- tail iteration (k=TSEQ): decoder peel A(0), prev = 0 -> base biases ----
    // s0[0] = h0_out(255); writes h0_dec(0) -> s0[1]. Overlaps B's enc step 255.
    {
      const half8 a0 = ldh8(&s0[0][c][q * 8]);
      const half8 a1 = ldh8(&s0[0][c][32 + q * 8]);
      const floatx4 TR = {bR0, bR0, bR0, bR0}, TZ = {bZ0, bZ0, bZ0, bZ0};
      const floatx4 T3 = {b30, b30, b30, b30};
      floatx4 aR, aZ, a3;
      floatx4 a4 = {b40, b40, b40, b40};
      PASS2_I3(a0, a1, aR, aZ, a3, W1d, TR, TZ, T3);
      #pragma unroll
      for (int r4 = 0; r4 < 4; r4++) {
        float gr, gz;
        sigm2pair(aR[r4], aZ[r4], gr, gz);
        const float nn = tanh2(a4[r4] + gr * a3[r4]);
        const float hn = nn + gz * (hr[r4] - nn);
        hr[r4] = hn;
        s0[1][q * 4 + r4][u] = (_Float16)hn;
      }
      SYNC();   // bar0: h0_dec(0) visible; B(0) runs in the next window
    }
    // ---- decoder steady: d = 1..179 (i_ = TSEQ+d), 2 barriers per step ----
    QR = (floatx4){dR, dR, dR, dR}; QZ = (floatx4){dZ, dZ, dZ, dZ};
    Q3 = (floatx4){d3, d3, d3, d3}; Q4 = (floatx4){d4, d4, d4, d4};
    for (int i_ = TSEQ + 1; i_ < TSEQ + TDEC; i_++) {
      const int p = i_ & 3, pn = (i_ + 1) & 3;
      // prepass (overlaps B finishing d-1): Whh0d.h0_dec(d-1)
      const half8 a0 = ldh8(&s0[p][c][q * 8]);
      const half8 a1 = ldh8(&s0[p][c][32 + q * 8]);
      floatx4 aR, aZ, a3, a4;
      PASS2_I3(a0, a1, aR, aZ, a3, W1d, QR, QZ, Q3);
      SYNC();                                          // B(d-1) done -> s1[p] = h1(d-1)
      const half8 b0 = ldh8(&s1[p][c][q * 8]);         // rank-1 head fold: W'.h1(d-1)
      const half8 b1 = ldh8(&s1[p][c][32 + q * 8]);
      PASS2_A2I1(b0, b1, aR, aZ, a4, W2d, Q4);
      #pragma unroll
      for (int r4 = 0; r4 < 4; r4++) {
        float gr, gz;
        sigm2pair(aR[r4], aZ[r4], gr, gz);
        const float nn = tanh2(a4[r4] + gr * a3[r4]);
        const float hn = nn + gz * (hr[r4] - nn);
        hr[r4] = hn;
        s0[pn][q * 4 + r4][u] = (_Float16)hn;
      }
      SYNC();                                          // A(d) done -> s0[pn]
    }
    SYNC();   // match B's barrier after its last finish (B(179))
  } else {
    // =========================== group B: layer 1 ===========================
    floatx4 QR = {cR, cR, cR, cR}, QZ = {cZ, cZ, cZ, cZ};
    floatx4 Q3 = {c3, c3, c3, c3}, Q4 = {c4, c4, c4, c4};
    // ============ encoder: iteration kk computes h1_out(kk-1), kk>=1 ============
    for (int k = 0; k < TSEQ; k += 4) {
      #pragma unroll
      for (int h4 = 0; h4 < 4; h4++) {
        const int kk = k + h4;
        if (kk > 0) {
          const int p = (h4 + 3) & 3, pn = h4;         // read s1[(kk-1)&3], s0[kk&3]
          const half8 f0 = ldh8(&s1[p][c][q * 8]);
          const half8 f1 = ldh8(&s1[p][c][32 + q * 8]);
          floatx4 aR, aZ, a3, a4;
          PASS2_I3(f0, f1, aR, aZ, a4, W2, QR, QZ, Q4);  // Whh1.h1 -> gh
          const half8 g0 = ldh8(&s0[pn][c][q * 8]);      // h0_out(kk-1), from prev window
          const half8 g1 = ldh8(&s0[pn][c][32 + q * 8]);
          PASS2_A2I1(g0, g1, aR, aZ, a3, W1, Q3);        // Wih1.h0 -> gi
          #pragma unroll
          for (int r4 = 0; r4 < 4; r4++) {
            float gr, gz;
            sigm2pair(aR[r4], aZ[r4], gr, gz);
            const float nn = tanh2(a3[r4] + gr * a4[r4]);
            const float hn = nn + gz * (hr[r4] - nn);
            hr[r4] = hn;
            s1[pn][q * 4 + r4][u] = (_Float16)hn;
          }
        }
        SYNC();
      }
    }
    // ---- tail iteration (kk=TSEQ): encoder step i_=255: s1[3], s0[0] -> s1[0] ----
    {
      const half8 f0 = ldh8(&s1[3][c][q * 8]);
      const half8 f1 = ldh8(&s1[3][c][32 + q * 8]);
      floatx4 aR, aZ, a3, a4;
      PASS2_I3(f0, f1, aR, aZ, a4, W2, QR, QZ, Q4);
      const half8 g0 = ldh8(&s0[0][c][q * 8]);
      const half8 g1 = ldh8(&s0[0][c][32 + q * 8]);
      PASS2_A2I1(g0, g1, aR, aZ, a3, W1, Q3);
      #pragma unroll
      for (int r4 = 0; r4 < 4; r4++) {
        float gr, gz;
        sigm2pair(aR[r4], aZ[r4], gr, gz);
        const float nn = tanh2(a3[r4] + gr * a4[r4]);
        const float hn = nn + gz * (hr[r4] - nn);
        hr[r4] = hn;
        s1[0][q * 4 + r4][u] = (_Float16)hn;
      }
      SYNC();   // bar0
    }
    // ---- transition: load decoder weights + consts (once; L2-hit) ----
    half8 W1d[3][2], W2d[3][2];
    loadW64(dWih1, W1d); loadW64(dWhh1, W2d);
    const float dR = L2E * (dbih1[u] + dbhh1[u]);
    const float dZ = L2E * (dbih1[64 + u] + dbhh1[64 + u]);
    const float d3 = 2.0f * L2E * dbih1[128 + u];
    const float d4 = 2.0f * L2E * dbhh1[128 + u];
    QR = (floatx4){dR, dR, dR, dR}; QZ = (floatx4){dZ, dZ, dZ, dZ};
    Q3 = (floatx4){d3, d3, d3, d3}; Q4 = (floatx4){d4, d4, d4, d4};
    // ---- B(0): s1[0] = h1_out(255), s0[1] = h0_dec(0) -> s1[1] = h1_dec(0) ----
    {
      const half8 f0 = ldh8(&s1[0][c][q * 8]);
      const half8 f1 = ldh8(&s1[0][c][32 + q * 8]);
      floatx4 aR, aZ, a3, a4;
      PASS2_I3(f0, f1, aR, aZ, a4, W2d, QR, QZ, Q4);
      const half8 g0 = ldh8(&s0[1][c][q * 8]);
      const half8 g1 = ldh8(&s0[1][c][32 + q * 8]);
      PASS2_A2I1(g0, g1, aR, aZ, a3, W1d, Q3);
      #pragma unroll
      for (int r4 = 0; r4 < 4; r4++) {
        float gr, gz;
        sigm2pair(aR[r4], aZ[r4], gr, gz);
        const float nn = tanh2(a3[r4] + gr * a4[r4]);
        const float hn = nn + gz * (hr[r4] - nn);
        hr[r4] = hn;
        s1[1][q * 4 + r4][u] = (_Float16)hn;
      }
      SYNC();   // bar1: h1_dec(0) visible
    }
    // ---- decoder steady: d = 1..179 (i_ = TSEQ+d), 2 barriers per step ----
    for (int i_ = TSEQ + 1; i_ < TSEQ + TDEC; i_++) {
      const int p = i_ & 3, pn = (i_ + 1) & 3;
      // prepass (overlaps A finishing d): Whh1d.h1_dec(d-1), + head cv(d-1)
      const half8 f0 = ldh8(&s1[p][c][q * 8]);
      const half8 f1 = ldh8(&s1[p][c][32 + q * 8]);
      floatx4 aR, aZ, a3, a4;
      PASS2_I3(f0, f1, aR, aZ, a4, W2d, QR, QZ, Q4);   // Whh1.h1 -> gh
      if (wvL == 0) {   // head: cv(d-1) from h1_dec(d-1) fragments (off critical path)
        const floatx4 wa = *(const floatx4*)&swk[q * 8];
        const floatx4 wb = *(const floatx4*)&swk[q * 8 + 4];
        const floatx4 wc = *(const floatx4*)&swk[32 + q * 8];
        const floatx4 we = *(const floatx4*)&swk[32 + q * 8 + 4];
        float cv = 0.0f;
        #pragma unroll
        for (int j = 0; j < 4; j++) {
          cv = fmaf((float)f0[j], wa[j], cv);
          cv = fmaf((float)f0[j + 4], wb[j], cv);
          cv = fmaf((float)f1[j], wc[j], cv);
          cv = fmaf((float)f1[j + 4], we[j], cv);
        }
        cv += __shfl_xor(cv, 16);
        cv += __shfl_xor(cv, 32);
        if (lane < GROWS) out[(base + lane) * TDEC + (i_ - TSEQ - 1)] = cv + ob;
      }
      SYNC();                                          // A(d) done -> s0[pn] = h0_dec(d)
      const half8 g0 = ldh8(&s0[pn][c][q * 8]);
      const half8 g1 = ldh8(&s0[pn][c][32 + q * 8]);
      PASS2_A2I1(g0, g1, aR, aZ, a3, W1d, Q3);         // Wih1.h0 -> gi
      #pragma unroll
      for (int r4 = 0; r4 < 4; r4++) {
        float gr, gz;
        sigm2pair(aR[r4], aZ[r4], gr, gz);
        const float nn = tanh2(a3[r4] + gr * a4[r4]);
        const float hn = nn + gz * (hr[r4] - nn);
        hr[r4] = hn;
        s1[pn][q * 4 + r4][u] = (_Float16)hn;
      }
      SYNC();                                          // B(d) done -> s1[pn]
    }
    // final head value: cv(179) from h1_dec(179) in s1[(436)&3 = 0]
    if (wvL == 0) {
      const half8 f0 = ldh8(&s1[0][c][q * 8]);
      const half8 f1 = ldh8(&s1[0][c][32 + q * 8]);
      const floatx4 wa = *(const floatx4*)&swk[q * 8];
      const floatx4 wb = *(const floatx4*)&swk[q * 8 + 4];
      const floatx4 wc = *(const floatx4*)&swk[32 + q * 8];
      const floatx4 we = *(const floatx4*)&swk[32 + q * 8 + 4];
      float cv = 0.0f;
      #pragma unroll
      for (int j = 0; j < 4; j++) {
        cv = fmaf((float)f0[j], wa[j], cv);
        cv = fmaf((float)f0[j + 4], wb[j], cv);
        cv = fmaf((float)f1[j], wc[j], cv);
        cv = fmaf((float)f1[j + 4], we[j], cv);
      }
      cv += __shfl_xor(cv, 16);
      cv += __shfl_xor(cv, 32);
      if (lane < GROWS) out[(base + lane) * TDEC + (TDEC - 1)] = cv + ob;
    }
  }
}

extern "C" void kernel_launch(void* const* d_in, const int* in_sizes, int n_in,
                              void* d_out, int out_size, void* d_ws, size_t ws_size,
                              hipStream_t stream) {
  (void)in_sizes; (void)n_in; (void)d_ws; (void)ws_size; (void)out_size;
  const float* x     = (const float*)d_in[0];
  const float* eWih0 = (const float*)d_in[1];
  const float* eWhh0 = (const float*)d_in[2];
  const float* ebih0 = (const float*)d_in[3];
  const float* ebhh0 = (const float*)d_in[4];
  const float* eWih1 = (const float*)d_in[5];
  const float* eWhh1 = (const float*)d_in[6];
  const float* ebih1 = (const float*)d_in[7];
  const float* ebhh1 = (const float*)d_in[8];
  const float* dWih0 = (const float*)d_in[9];
  const float* dWhh0 = (const float*)d_in[10];
  const float* dbih0 = (const float*)d_in[11];
  const float* dbhh0 = (const float*)d_in[12];
  const float* dWih1 = (const float*)d_in[13];
  const float* dWhh1 = (const float*)d_in[14];
  const float* dbih1 = (const float*)d_in[15];
  const float* dbhh1 = (const float*)d_in[16];
  const float* outW  = (const float*)d_in[17];
  const float* outB  = (const float*)d_in[18];
  hipLaunchKernelGGL(gru_persist, dim3(NBLK), dim3(512), 0, stream,
                     x, eWih0, eWhh0, ebih0, ebhh0, eWih1, eWhh1, ebih1, ebhh1,
                     dWih0, dWhh0, dbih0, dbhh0, dWih1, dWhh1, dbih1, dbhh1,
                     outW, outB, (float*)d_out);
}

// Round 8
// 421.411 us; speedup vs baseline: 1.4615x; 1.2683x over previous
//
#include <hip/hip_runtime.h>
#include <cstdint>

typedef _Float16 half8 __attribute__((ext_vector_type(8)));
typedef __attribute__((ext_vector_type(4))) float floatx4;

#define TSEQ 256
#define TDEC 180
#define NIN  6
#define GROWS 16
#define NBLK (4096 / GROWS)
#define NSL 4     // state buffer depth: h(j) lives in slot (j+1)&3
#define RS0 104   // s0 row stride (halfs): cols 0..63 h0, 64..95 x|0, 96..103 pad
#define RS1 72    // s1 row stride
#define L2E 1.4426950408889634f

// ============================================================================
// Merged-wave design (R8): ONE group of 4 waves; each wave computes BOTH GRU
// layers for its 16 gate-columns. 1 wave/SIMD -> no 2-wave lockstep contention:
// the wave's own MFMA-pipe work (~400cy) and nonlin VALU burst (~500cy) overlap
// via ILP instead of two waves serializing phase-by-phase (R1-R4: 1170cy/window).
// Encoder window i computes h0(i) AND h1(i-1); layer1 reuses the same h0(i-1)
// fragment layer0 reads. Barrier schedule is UNIFORM across waves (1/window).
// ============================================================================

__device__ __forceinline__ floatx4 mfma16(half8 a, half8 b, floatx4 c) {
  return __builtin_amdgcn_mfma_f32_16x16x32_f16(a, b, c, 0, 0, 0);
}

// pre-scaled transcendentals: inputs already carry log2e (sigm) / 2*log2e (tanh)
// Shared-rcp sigmoid pair: one rcp serves both r and z gates.
__device__ __forceinline__ void sigm2pair(float vr, float vz, float& gr, float& gz) {
  const float d1 = 1.0f + __builtin_amdgcn_exp2f(-vr);
  const float d2 = 1.0f + __builtin_amdgcn_exp2f(-vz);
  const float rp = __builtin_amdgcn_rcpf(d1 * d2);
  gr = rp * d2;
  gz = rp * d1;
}
__device__ __forceinline__ float tanh2(float v) {
  return fmaf(2.0f, __builtin_amdgcn_rcpf(1.0f + __builtin_amdgcn_exp2f(-v)), -1.0f);
}

__device__ __forceinline__ half8 ldh8(const _Float16* p) { return *(const half8*)p; }
__device__ __forceinline__ floatx4 sp4(float v) { return (floatx4){v, v, v, v}; }

#define PASS2_I3(F0, F1, r, z, g, W, QR, QZ, QG) do {                   \
  r = mfma16(F0, W[0][0], QR); z = mfma16(F0, W[1][0], QZ); g = mfma16(F0, W[2][0], QG); \
  r = mfma16(F1, W[0][1], r);  z = mfma16(F1, W[1][1], z);  g = mfma16(F1, W[2][1], g);  \
} while (0)

#define PASS2_A2I1(F0, F1, r, z, g, W, QG) do {                         \
  r = mfma16(F0, W[0][0], r); z = mfma16(F0, W[1][0], z); g = mfma16(F0, W[2][0], QG); \
  r = mfma16(F1, W[0][1], r); z = mfma16(F1, W[1][1], z); g = mfma16(F1, W[2][1], g);  \
} while (0)

// layer0 x-pass: only the first K-half is nonzero (x has 6 features) -> 1-D W.
#define PASS1_I1(F0, r, z, g, W3, QG) do {                              \
  r = mfma16(F0, W3[0], r); z = mfma16(F0, W3[1], z); g = mfma16(F0, W3[2], QG); \
} while (0)

// Lockstep barrier: drain this wave's LDS ops (writes become visible), then
// raw s_barrier. Deliberately NO vmcnt drain so global prefetch loads stay in
// flight across barriers. Memory clobbers pin LDS ops on each side.
#define SYNC() do {                                         \
  asm volatile("s_waitcnt lgkmcnt(0)" ::: "memory");        \
  __builtin_amdgcn_s_barrier();                             \
  asm volatile("" ::: "memory");                            \
} while (0)

__global__ void __launch_bounds__(256, 1)
gru_persist(const float* __restrict__ x,
            const float* __restrict__ eWih0, const float* __restrict__ eWhh0,
            const float* __restrict__ ebih0, const float* __restrict__ ebhh0,
            const float* __restrict__ eWih1, const float* __restrict__ eWhh1,
            const float* __restrict__ ebih1, const float* __restrict__ ebhh1,
            const float* __restrict__ dWih0, const float* __restrict__ dWhh0,
            const float* __restrict__ dbih0, const float* __restrict__ dbhh0,
            const float* __restrict__ dWih1, const float* __restrict__ dWhh1,
            const float* __restrict__ dbih1, const float* __restrict__ dbhh1,
            const float* __restrict__ outW, const float* __restrict__ outB,
            float* __restrict__ out)
{
  __shared__ __align__(16) _Float16 s0[NSL][16][RS0];
  __shared__ __align__(16) _Float16 s1[NSL][16][RS1];

  const int tid  = threadIdx.x;
  const int wvL  = tid >> 6;           // wave 0..3: owns gate-cols [wvL*16, wvL*16+16)
  const int lane = tid & 63;
  const int c    = lane & 15;
  const int q    = lane >> 4;
  const int u    = wvL * 16 + c;
  const long base = (long)blockIdx.x * GROWS;

  for (int i = tid; i < NSL * 16 * RS0; i += 256) ((uint16_t*)s0)[i] = 0;
  for (int i = tid; i < NSL * 16 * RS1; i += 256) ((uint16_t*)s1)[i] = 0;
  if (tid < GROWS * NIN) {  // x(0) -> s0[0]
    int m = tid / 6, i2 = tid - m * 6;
    s0[0][m][64 + i2] = (_Float16)x[(base + m) * (TSEQ * NIN) + i2];
  }

  // ---- encoder weights (decoder weights loaded at the transition) ----
  half8 W1[3][2];    // Whh0
  half8 W2e[3];      // Wih0 fold, first K-half only
  half8 W1B[3][2];   // Wih1
  half8 W2B[3][2];   // Whh1
  float hr0[4] = {0, 0, 0, 0};   // f32 h0 carry (rows q*4+r4, col u)
  float hr1[4] = {0, 0, 0, 0};   // f32 h1 carry
  const float SC[3] = {L2E, L2E, 2.0f * L2E};   // r, z, n row scales (fold exp2 args)

  auto loadW64 = [&](const float* W, half8 (&D)[3][2]) {
    #pragma unroll
    for (int s = 0; s < 3; s++) {
      const int n = (s * 4 + wvL) * 16 + c;
      #pragma unroll
      for (int kt = 0; kt < 2; kt++) {
        const int k0 = kt * 32 + q * 8;
        #pragma unroll
        for (int j = 0; j < 8; j++) D[s][kt][j] = (_Float16)(SC[s] * W[n * 64 + k0 + j]);
      }
    }
  };

  loadW64(eWhh0, W1);
  #pragma unroll
  for (int s = 0; s < 3; s++) {
    const int n = (s * 4 + wvL) * 16 + c;
    #pragma unroll
    for (int j = 0; j < 8; j++) {
      float v = (q == 0 && j < NIN) ? SC[s] * eWih0[n * NIN + j] : 0.0f;
      W2e[s][j] = (_Float16)v;
    }
  }
  loadW64(eWih1, W1B);
  loadW64(eWhh1, W2B);

  const float ob = outB[0];
  float wk[2][8];   // head weights (used by wave 0 only)
  #pragma unroll
  for (int kt = 0; kt < 2; kt++)
    #pragma unroll
    for (int j = 0; j < 8; j++) wk[kt][j] = outW[kt * 32 + q * 8 + j];

  // encoder consts: layer0 (gh const = ebhh0 n-row, gi const = ebih0 n-row)
  const floatx4 QR0 = sp4(L2E * (ebih0[u] + ebhh0[u]));
  const floatx4 QZ0 = sp4(L2E * (ebih0[64 + u] + ebhh0[64 + u]));
  const floatx4 Q30 = sp4(2.0f * L2E * ebhh0[128 + u]);
  const floatx4 Q40 = sp4(2.0f * L2E * ebih0[128 + u]);
  // layer1 (gi const = ebih1, gh const = ebhh1)
  const floatx4 QR1 = sp4(L2E * (ebih1[u] + ebhh1[u]));
  const floatx4 QZ1 = sp4(L2E * (ebih1[64 + u] + ebhh1[64 + u]));
  const floatx4 Q31 = sp4(2.0f * L2E * ebih1[128 + u]);
  const floatx4 Q41 = sp4(2.0f * L2E * ebhh1[128 + u]);

  __syncthreads();   // everything after runs on the uniform 1-barrier/window schedule

  // ---- x prefetch, spread over all 4 waves (lanes 0..23, 1 slot each, depth 2)
  const bool doX = (lane < 24);
  const float *px0 = nullptr;
  int xo0 = 0;
  float xa0 = 0.f, xb0 = 0.f;
  if (doX) {
    int s_ = wvL * 24 + lane;                 // 96 slots = 16 rows x 6 features
    int m0 = s_ / 6, i0 = s_ - m0 * 6;
    px0 = x + (base + m0) * (TSEQ * NIN) + i0;
    xo0 = m0 * RS0 + 64 + i0;
    xa0 = px0[NIN];       // x(1)
    xb0 = px0[2 * NIN];   // x(2)
  }

  // ============ encoder: window i computes h0(i) AND h1(i-1) ============
  // slots: h0(i-1) & x(i) in s0[i&3]; h0(i) -> s0[(i+1)&3];
  //        h1(i-2) in s1[(i-1)&3]; h1(i-1) -> s1[i&3].
  for (int k = 0; k < TSEQ; k += 4) {
    #pragma unroll
    for (int h4 = 0; h4 < 4; h4++) {
      const int i_ = k + h4;
      const int p  = h4;             // i&3
      const int pn = (h4 + 1) & 3;   // (i+1)&3
      const int pm = (h4 + 3) & 3;   // (i-1)&3
      const half8 a0 = ldh8(&s0[p][c][q * 8]);        // h0(i-1) frag (shared by both layers)
      const half8 a1 = ldh8(&s0[p][c][32 + q * 8]);
      const half8 xf = ldh8(&s0[p][c][64 + q * 8]);   // x(i)
      floatx4 aR, aZ, a3, a4;
      PASS2_I3(a0, a1, aR, aZ, a3, W1, QR0, QZ0, Q30);  // Whh0.h0 -> gh
      PASS1_I1(xf, aR, aZ, a4, W2e, Q40);               // Wih0.x  -> gi
      floatx4 fR, fZ, fG, fI;
      if (i_ > 0) {
        const half8 f0 = ldh8(&s1[pm][c][q * 8]);       // h1(i-2) frag
        const half8 f1 = ldh8(&s1[pm][c][32 + q * 8]);
        PASS2_I3(f0, f1, fR, fZ, fG, W2B, QR1, QZ1, Q41);  // Whh1.h1 -> gh
        PASS2_A2I1(a0, a1, fR, fZ, fI, W1B, Q31);          // Wih1.h0 -> gi
      }
      if (doX && i_ + 1 < TSEQ) {
        ((_Float16*)s0[pn])[xo0] = (_Float16)xa0;
        xa0 = xb0;
        if (i_ + 3 < TSEQ) xb0 = px0[(i_ + 3) * NIN];
      }
      // layer0 nonlin -> h0(i)
      #pragma unroll
      for (int r4 = 0; r4 < 4; r4++) {
        float gr, gz;
        sigm2pair(aR[r4], aZ[r4], gr, gz);
        const float nn = tanh2(a4[r4] + gr * a3[r4]);
        const float hn = nn + gz * (hr0[r4] - nn);
        hr0[r4] = hn;
        s0[pn][q * 4 + r4][u] = (_Float16)hn;
      }
      // layer1 nonlin -> h1(i-1)
      if (i_ > 0) {
        #pragma unroll
        for (int r4 = 0; r4 < 4; r4++) {
          float gr, gz;
          sigm2pair(fR[r4], fZ[r4], gr, gz);
          const float nn = tanh2(fI[r4] + gr * fG[r4]);
          const float hn = nn + gz * (hr1[r4] - nn);
          hr1[r4] = hn;
          s1[p][q * 4 + r4][u] = (_Float16)hn;
        }
      }
      SYNC();
    }
  }
  // ---- drain window: h1(255) = cell(h0(255) [s0[0]], h1(254) [s1[3]]) -> s1[0] ----
  {
    const half8 g0 = ldh8(&s0[0][c][q * 8]);
    const half8 g1 = ldh8(&s0[0][c][32 + q * 8]);
    const half8 f0 = ldh8(&s1[3][c][q * 8]);
    const half8 f1 = ldh8(&s1[3][c][32 + q * 8]);
    floatx4 fR, fZ, fG, fI;
    PASS2_I3(f0, f1, fR, fZ, fG, W2B, QR1, QZ1, Q41);
    PASS2_A2I1(g0, g1, fR, fZ, fI, W1B, Q31);
    #pragma unroll
    for (int r4 = 0; r4 < 4; r4++) {
      float gr, gz;
      sigm2pair(fR[r4], fZ[r4], gr, gz);
      const float nn = tanh2(fI[r4] + gr * fG[r4]);
      const float hn = nn + gz * (hr1[r4] - nn);
      hr1[r4] = hn;
      s1[0][q * 4 + r4][u] = (_Float16)hn;
    }
    SYNC();
  }

  // ---- transition: decoder weights + consts (once; L2-hit) ----
  half8 W1d[3][2], W2d[3][2];     // layer0: Whh0d, rank-1 head fold
  half8 W1dB[3][2], W2dB[3][2];   // layer1: Wih1d, Whh1d
  loadW64(dWhh0, W1d);
  #pragma unroll
  for (int s = 0; s < 3; s++) {   // W2d = rank-1 head fold: SC[s] * dWih0[n] * outW[k]
    const int n = (s * 4 + wvL) * 16 + c;
    const float wd = SC[s] * dWih0[n];
    #pragma unroll
    for (int kt = 0; kt < 2; kt++) {
      const int k0 = kt * 32 + q * 8;
      #pragma unroll
      for (int j = 0; j < 8; j++) W2d[s][kt][j] = (_Float16)(wd * outW[k0 + j]);
    }
  }
  loadW64(dWih1, W1dB);
  loadW64(dWhh1, W2dB);
  const float bR0 = L2E * (dbih0[u] + dbhh0[u]);
  const float bZ0 = L2E * (dbih0[64 + u] + dbhh0[64 + u]);
  const float b30 = 2.0f * L2E * dbhh0[128 + u];
  const float b40 = 2.0f * L2E * dbih0[128 + u];
  const floatx4 QRd = sp4(bR0 + L2E * (dWih0[u] * ob));
  const floatx4 QZd = sp4(bZ0 + L2E * (dWih0[64 + u] * ob));
  const floatx4 Q3d = sp4(b30);
  const floatx4 Q4d = sp4(b40 + 2.0f * L2E * (dWih0[128 + u] * ob));
  const floatx4 QR1d = sp4(L2E * (dbih1[u] + dbhh1[u]));
  const floatx4 QZ1d = sp4(L2E * (dbih1[64 + u] + dbhh1[64 + u]));
  const floatx4 Q31d = sp4(2.0f * L2E * dbih1[128 + u]);
  const floatx4 Q41d = sp4(2.0f * L2E * dbhh1[128 + u]);

  // ---- peel: h0_dec(0), prev = 0 -> base biases; s0[0]=h0(255) -> s0[1] ----
  {
    const half8 a0 = ldh8(&s0[0][c][q * 8]);
    const half8 a1 = ldh8(&s0[0][c][32 + q * 8]);
    const floatx4 TR = sp4(bR0), TZ = sp4(bZ0), T3 = sp4(b30);
    floatx4 aR, aZ, a3;
    PASS2_I3(a0, a1, aR, aZ, a3, W1d, TR, TZ, T3);
    #pragma unroll
    for (int r4 = 0; r4 < 4; r4++) {
      float gr, gz;
      sigm2pair(aR[r4], aZ[r4], gr, gz);
      const float nn = tanh2(b40 + gr * a3[r4]);
      const float hn = nn + gz * (hr0[r4] - nn);
      hr0[r4] = hn;
      s0[1][q * 4 + r4][u] = (_Float16)hn;
    }
    SYNC();
  }
  // ---- h1_dec(0) = cell(h0_dec(0) [s0[1]], h1_enc(255) [s1[0]]) -> s1[1] ----
  {
    const half8 f0 = ldh8(&s1[0][c][q * 8]);
    const half8 f1 = ldh8(&s1[0][c][32 + q * 8]);
    const half8 g0 = ldh8(&s0[1][c][q * 8]);
    const half8 g1 = ldh8(&s0[1][c][32 + q * 8]);
    floatx4 fR, fZ, fG, fI;
    PASS2_I3(f0, f1, fR, fZ, fG, W2dB, QR1d, QZ1d, Q41d);
    PASS2_A2I1(g0, g1, fR, fZ, fI, W1dB, Q31d);
    #pragma unroll
    for (int r4 = 0; r4 < 4; r4++) {
      float gr, gz;
      sigm2pair(fR[r4], fZ[r4], gr, gz);
      const float nn = tanh2(fI[r4] + gr * fG[r4]);
      const float hn = nn + gz * (hr1[r4] - nn);
      hr1[r4] = hn;
      s1[1][q * 4 + r4][u] = (_Float16)hn;
    }
    SYNC();
  }
  // ---- decoder steady: d = 1..179 (i_ = TSEQ+d), 2 windows per step ----
  for (int i_ = TSEQ + 1; i_ < TSEQ + TDEC; i_++) {
    const int p = i_ & 3, pn = (i_ + 1) & 3;
    // window 1: h0_dec(d) from h0(d-1) [s0[p]] + rank-1 head fold of h1(d-1) [s1[p]]
    const half8 a0 = ldh8(&s0[p][c][q * 8]);
    const half8 a1 = ldh8(&s0[p][c][32 + q * 8]);
    const half8 b0 = ldh8(&s1[p][c][q * 8]);   // h1(d-1) frag: kept for window 2
    const half8 b1 = ldh8(&s1[p][c][32 + q * 8]);
    floatx4 aR, aZ, a3, a4;
    PASS2_I3(a0, a1, aR, aZ, a3, W1d, QRd, QZd, Q3d);
    PASS2_A2I1(b0, b1, aR, aZ, a4, W2d, Q4d);
    if (wvL == 0) {   // head: cv(d-1) from h1(d-1) fragments (off critical path)
      float cv = 0.0f;
      #pragma unroll
      for (int j = 0; j < 8; j++) {
        cv = fmaf((float)b0[j], wk[0][j], cv);
        cv = fmaf((float)b1[j], wk[1][j], cv);
      }
      cv += __shfl_xor(cv, 16);
      cv += __shfl_xor(cv, 32);
      if (lane < 16) out[(base + lane) * TDEC + (i_ - TSEQ - 1)] = cv + ob;
    }
    #pragma unroll
    for (int r4 = 0; r4 < 4; r4++) {
      float gr, gz;
      sigm2pair(aR[r4], aZ[r4], gr, gz);
      const float nn = tanh2(a4[r4] + gr * a3[r4]);
      const float hn = nn + gz * (hr0[r4] - nn);
      hr0[r4] = hn;
      s0[pn][q * 4 + r4][u] = (_Float16)hn;
    }
    SYNC();                                   // h0_dec(d) visible
    // window 2: h1_dec(d) from h0(d) [s0[pn]] + h1(d-1) [b0/b1 still in regs]
    const half8 g0 = ldh8(&s0[pn][c][q * 8]);
    const half8 g1 = ldh8(&s0[pn][c][32 + q * 8]);
    floatx4 fR, fZ, fG, fI;
    PASS2_I3(b0, b1, fR, fZ, fG, W2dB, QR1d, QZ1d, Q41d);  // Whh1d.h1(d-1) -> gh
    PASS2_A2I1(g0, g1, fR, fZ, fI, W1dB, Q31d);            // Wih1d.h0(d)  -> gi
    #pragma unroll
    for (int r4 = 0; r4 < 4; r4++) {
      float gr, gz;
      sigm2pair(fR[r4], fZ[r4], gr, gz);
      const float nn = tanh2(fI[r4] + gr * fG[r4]);
      const float hn = nn + gz * (hr1[r4] - nn);
      hr1[r4] = hn;
      s1[pn][q * 4 + r4][u] = (_Float16)hn;
    }
    SYNC();                                   // h1_dec(d) visible
  }
  // ---- final head: cv(179) from h1_dec(179) in s1[(436)&3 = 0] ----
  if (wvL == 0) {
    const half8 f0 = ldh8(&s1[0][c][q * 8]);
    const half8 f1 = ldh8(&s1[0][c][32 + q * 8]);
    float cv = 0.0f;
    #pragma unroll
    for (int j = 0; j < 8; j++) {
      cv = fmaf((float)f0[j], wk[0][j], cv);
      cv = fmaf((float)f1[j], wk[1][j], cv);
    }
    cv += __shfl_xor(cv, 16);
    cv += __shfl_xor(cv, 32);
    if (lane < 16) out[(base + lane) * TDEC + (TDEC - 1)] = cv + ob;
  }
}

extern "C" void kernel_launch(void* const* d_in, const int* in_sizes, int n_in,
                              void* d_out, int out_size, void* d_ws, size_t ws_size,
                              hipStream_t stream) {
  (void)in_sizes; (void)n_in; (void)d_ws; (void)ws_size; (void)out_size;
  const float* x     = (const float*)d_in[0];
  const float* eWih0 = (const float*)d_in[1];
  const float* eWhh0 = (const float*)d_in[2];
  const float* ebih0 = (const float*)d_in[3];
  const float* ebhh0 = (const float*)d_in[4];
  const float* eWih1 = (const float*)d_in[5];
  const float* eWhh1 = (const float*)d_in[6];
  const float* ebih1 = (const float*)d_in[7];
  const float* ebhh1 = (const float*)d_in[8];
  const float* dWih0 = (const float*)d_in[9];
  const float* dWhh0 = (const float*)d_in[10];
  const float* dbih0 = (const float*)d_in[11];
  const float* dbhh0 = (const float*)d_in[12];
  const float* dWih1 = (const float*)d_in[13];
  const float* dWhh1 = (const float*)d_in[14];
  const float* dbih1 = (const float*)d_in[15];
  const float* dbhh1 = (const float*)d_in[16];
  const float* outW  = (const float*)d_in[17];
  const float* outB  = (const float*)d_in[18];
  hipLaunchKernelGGL(gru_persist, dim3(NBLK), dim3(256), 0, stream,
                     x, eWih0, eWhh0, ebih0, ebhh0, eWih1, eWhh1, ebih1, ebhh1,
                     dWih0, dWhh0, dbih0, dbhh0, dWih1, dWhh1, dbih1, dbhh1,
                     outW, outB, (float*)d_out);
}

// Round 9
// 346.801 us; speedup vs baseline: 1.7759x; 1.2151x over previous
//
#include <hip/hip_runtime.h>
#include <cstdint>

typedef _Float16 half8 __attribute__((ext_vector_type(8)));
typedef _Float16 half4v __attribute__((ext_vector_type(4)));
typedef __attribute__((ext_vector_type(4))) float floatx4;
typedef __attribute__((ext_vector_type(2))) float float2v;

#define TSEQ 256
#define TDEC 180
#define NIN  6
#define GROWS 16
#define NBLK (4096 / GROWS)
#define NSL 4     // state buffer depth: h(j) lives in slot (j+1)&3
#define RS0 104   // s0 row stride (halfs): cols 0..63 h0, 64..95 x|0, 96..103 pad
#define RS1 72    // s1 row stride
#define L2E 1.4426950408889634f

__device__ __forceinline__ floatx4 mfma16(half8 a, half8 b, floatx4 c) {
  return __builtin_amdgcn_mfma_f32_16x16x32_f16(a, b, c, 0, 0, 0);
}

__device__ __forceinline__ half8 ldh8(const _Float16* p) { return *(const half8*)p; }

// ---- OPERAND-SWAPPED MFMA passes: compute gates^T = W_tile . h^T ----
// Identical dot products / K-order as mfma(h, W) (bit-identical results);
// C layout becomes (row = gate-within-tile = q*4+r4, col = batch row = c), so
// each lane's 4 nonlin outputs land on 4 CONSECUTIVE h-columns of one batch
// row -> single ds_write_b64 instead of 4x ds_write_b16.
#define PASS2_I3(F0, F1, r, z, g, W, QR, QZ, QG) do {                   \
  r = mfma16(W[0][0], F0, QR); z = mfma16(W[1][0], F0, QZ); g = mfma16(W[2][0], F0, QG); \
  r = mfma16(W[0][1], F1, r);  z = mfma16(W[1][1], F1, z);  g = mfma16(W[2][1], F1, g);  \
} while (0)

#define PASS2_A2I1(F0, F1, r, z, g, W, QG) do {                         \
  r = mfma16(W[0][0], F0, r); z = mfma16(W[1][0], F0, z); g = mfma16(W[2][0], F0, QG); \
  r = mfma16(W[0][1], F1, r); z = mfma16(W[1][1], F1, z); g = mfma16(W[2][1], F1, g);  \
} while (0)

// layer0 x-pass: only the first K-half is nonzero (x has 6 features) -> 1-D W.
#define PASS1_I1(F0, r, z, g, W3, QG) do {                              \
  r = mfma16(W3[0], F0, r); z = mfma16(W3[1], F0, z); g = mfma16(W3[2], F0, QG); \
} while (0)

// Lockstep barrier: drain this wave's LDS ops (writes become visible), then
// raw s_barrier. Deliberately NO vmcnt drain so global prefetch loads stay in
// flight across barriers. Memory clobbers pin LDS ops on each side.
#define SYNC() do {                                         \
  asm volatile("s_waitcnt lgkmcnt(0)" ::: "memory");        \
  __builtin_amdgcn_s_barrier();                             \
  asm volatile("" ::: "memory");                            \
} while (0)

__global__ void __launch_bounds__(512, 2)
gru_persist(const float* __restrict__ x,
            const float* __restrict__ eWih0, const float* __restrict__ eWhh0,
            const float* __restrict__ ebih0, const float* __restrict__ ebhh0,
            const float* __restrict__ eWih1, const float* __restrict__ eWhh1,
            const float* __restrict__ ebih1, const float* __restrict__ ebhh1,
            const float* __restrict__ dWih0, const float* __restrict__ dWhh0,
            const float* __restrict__ dbih0, const float* __restrict__ dbhh0,
            const float* __restrict__ dWih1, const float* __restrict__ dWhh1,
            const float* __restrict__ dbih1, const float* __restrict__ dbhh1,
            const float* __restrict__ outW, const float* __restrict__ outB,
            float* __restrict__ out)
{
  __shared__ __align__(16) _Float16 s0[NSL][16][RS0];
  __shared__ __align__(16) _Float16 s1[NSL][16][RS1];

  const int tid  = threadIdx.x;
  const bool isA = tid < 256;          // A = layer0 waves, B = layer1 waves
  const int wvL  = (tid >> 6) & 3;
  const int lane = tid & 63;
  const int c    = lane & 15;
  const int q    = lane >> 4;
  const int u    = wvL * 16 + c;       // gate ROW of this lane's W fragment
  const int ub   = wvL * 16 + q * 4;   // base h-col of this lane's 4 nonlin elems
  const long base = (long)blockIdx.x * GROWS;

  for (int i = tid; i < NSL * 16 * RS0; i += 512) ((uint16_t*)s0)[i] = 0;
  for (int i = tid; i < NSL * 16 * RS1; i += 512) ((uint16_t*)s1)[i] = 0;
  if (tid < GROWS * NIN) {  // x(0) -> s0[0]
    int m = tid / 6, i2 = tid - m * 6;
    s0[0][m][64 + i2] = (_Float16)x[(base + m) * (TSEQ * NIN) + i2];
  }

  // encoder + decoder weights ALL register-resident from the start
  half8 W1[3][2], W2[3][2];    // encoder: A: Whh0 / (W2 unused by A) | B: Wih1 / Whh1
  half8 W2e[3];                // A: Wih0 fold, first K-half only
  half8 W1d[3][2], W2d[3][2];  // decoder: A: Whh0d / rank-1 fold | B: Wih1d / Whh1d
  float hr[4] = {0, 0, 0, 0};
  const float SC[3] = {L2E, L2E, 2.0f * L2E};   // r, z, n row scales (fold exp2 args)

  auto loadW64 = [&](const float* W, half8 (&D)[3][2]) {
    #pragma unroll
    for (int s = 0; s < 3; s++) {
      const int n = (s * 4 + wvL) * 16 + c;
      #pragma unroll
      for (int kt = 0; kt < 2; kt++) {
        const int k0 = kt * 32 + q * 8;
        #pragma unroll
        for (int j = 0; j < 8; j++) D[s][kt][j] = (_Float16)(SC[s] * W[n * 64 + k0 + j]);
      }
    }
  };

  // Packed nonlin: nn = tanh(GIN + gr*GHN), hn = nn + gz*(h_old - nn).
  // float2 vector math -> v_pk_*_f32 where the compiler cooperates; shared-rcp
  // sigmoid pair per elem; shared-rcp tanh across the elem pair. Single b64 store.
  auto NLIN = [&](const floatx4 R, const floatx4 Z, const floatx4 GIN, const floatx4 GHN,
                  _Float16* dst) {
    half4v hv;
    #pragma unroll
    for (int pr = 0; pr < 2; pr++) {
      const int e = pr * 2;
      float2v er, ez;
      er.x = __builtin_amdgcn_exp2f(-R[e]);   er.y = __builtin_amdgcn_exp2f(-R[e + 1]);
      ez.x = __builtin_amdgcn_exp2f(-Z[e]);   ez.y = __builtin_amdgcn_exp2f(-Z[e + 1]);
      const float2v Dr = 1.0f + er, Dz = 1.0f + ez;
      const float2v P  = Dr * Dz;
      float2v rp;
      rp.x = __builtin_amdgcn_rcpf(P.x);      rp.y = __builtin_amdgcn_rcpf(P.y);
      const float2v gr = rp * Dz, gz = rp * Dr;
      const float2v gin = {GIN[e], GIN[e + 1]}, ghn = {GHN[e], GHN[e + 1]};
      const float2v vn = gin + gr * ghn;
      float2v en;
      en.x = __builtin_amdgcn_exp2f(-vn.x);   en.y = __builtin_amdgcn_exp2f(-vn.y);
      const float2v Dn = 1.0f + en;
      const float rpn = __builtin_amdgcn_rcpf(Dn.x * Dn.y);   // shared tanh rcp
      const float2v dsw = {Dn.y, Dn.x};
      const float2v nn = (2.0f * rpn) * dsw - 1.0f;
      const float2v hold = {hr[e], hr[e + 1]};
      const float2v hn = nn + gz * (hold - nn);
      hr[e] = hn.x; hr[e + 1] = hn.y;
      hv[e] = (_Float16)hn.x; hv[e + 1] = (_Float16)hn.y;
    }
    *(half4v*)dst = hv;
  };

  const float ob = outB[0];
  floatx4 QR, QZ, Q3, Q4;        // encoder consts (per-elem: gate = ub + r)
  floatx4 DRv, DZv, D3v, D4v;    // decoder steady consts
  floatx4 TRv, TZv, T3v, T4v;    // A decoder first-step consts
  float wk[2][8];                // B: head weights
  if (isA) {
    loadW64(eWhh0, W1);
    #pragma unroll
    for (int s = 0; s < 3; s++) {
      const int n = (s * 4 + wvL) * 16 + c;
      #pragma unroll
      for (int j = 0; j < 8; j++) {
        float v = (q == 0 && j < NIN) ? SC[s] * eWih0[n * NIN + j] : 0.0f;
        W2e[s][j] = (_Float16)v;
      }
    }
    loadW64(dWhh0, W1d);
    #pragma unroll
    for (int s = 0; s < 3; s++) {   // W2d = rank-1 head fold: SC[s] * dWih0[n] * outW[k]
      const int n = (s * 4 + wvL) * 16 + c;
      const float wd = SC[s] * dWih0[n];
      #pragma unroll
      for (int kt = 0; kt < 2; kt++) {
        const int k0 = kt * 32 + q * 8;
        #pragma unroll
        for (int j = 0; j < 8; j++) W2d[s][kt][j] = (_Float16)(wd * outW[k0 + j]);
      }
    }
    #pragma unroll
    for (int r = 0; r < 4; r++) {
      const int g = ub + r;
      QR[r] = L2E * (ebih0[g] + ebhh0[g]);
      QZ[r] = L2E * (ebih0[64 + g] + ebhh0[64 + g]);
      Q3[r] = 2.0f * L2E * ebhh0[128 + g];   // gh const
      Q4[r] = 2.0f * L2E * ebih0[128 + g];   // gi const
      TRv[r] = L2E * (dbih0[g] + dbhh0[g]);
      TZv[r] = L2E * (dbih0[64 + g] + dbhh0[64 + g]);
      T3v[r] = 2.0f * L2E * dbhh0[128 + g];
      T4v[r] = 2.0f * L2E * dbih0[128 + g];
      DRv[r] = TRv[r] + L2E * (dWih0[g] * ob);
      DZv[r] = TZv[r] + L2E * (dWih0[64 + g] * ob);
      D3v[r] = T3v[r];
      D4v[r] = T4v[r] + 2.0f * L2E * (dWih0[128 + g] * ob);
    }
  } else {
    loadW64(eWih1, W1); loadW64(eWhh1, W2);
    loadW64(dWih1, W1d); loadW64(dWhh1, W2d);
    #pragma unroll
    for (int r = 0; r < 4; r++) {
      const int g = ub + r;
      QR[r] = L2E * (ebih1[g] + ebhh1[g]);
      QZ[r] = L2E * (ebih1[64 + g] + ebhh1[64 + g]);
      Q3[r] = 2.0f * L2E * ebih1[128 + g];   // gi const
      Q4[r] = 2.0f * L2E * ebhh1[128 + g];   // gh const
      DRv[r] = L2E * (dbih1[g] + dbhh1[g]);
      DZv[r] = L2E * (dbih1[64 + g] + dbhh1[64 + g]);
      D3v[r] = 2.0f * L2E * dbih1[128 + g];
      D4v[r] = 2.0f * L2E * dbhh1[128 + g];
    }
    #pragma unroll
    for (int kt = 0; kt < 2; kt++)
      #pragma unroll
      for (int j = 0; j < 8; j++) wk[kt][j] = outW[kt * 32 + q * 8 + j];
  }
  __syncthreads();   // everything after runs on the lockstep barrier schedule

  // Barrier schedule (both sides execute exactly 616 SYNCs):
  //   encoder: 256 iters (1 SYNC each) + 1 tail iter (A: decoder peel, B: enc step 255)
  //   decoder: B(0) window (1 SYNC), then 179 iters x 2 SYNCs; A adds 1 trailing SYNC.
  if (isA) {
    // ---- x prefetch, spread over ALL 4 A-waves (lanes 0..23, 1 slot each, depth 2)
    const bool doX = (lane < 24);
    const float *px0 = nullptr;
    int xo0 = 0;
    float xa0 = 0.f, xb0 = 0.f;   // (xa=next-to-write, xb=following)
    if (doX) {
      int s_ = wvL * 24 + lane;                 // 96 slots = 16 rows x 6 features
      int m0 = s_ / 6, i0 = s_ - m0 * 6;
      px0 = x + (base + m0) * (TSEQ * NIN) + i0;
      xo0 = m0 * RS0 + 64 + i0;
      xa0 = px0[NIN];       // x(1)
      xb0 = px0[2 * NIN];   // x(2)
    }
    // ================= encoder: iteration k computes h0_out(k) =================
    for (int k = 0; k < TSEQ; k += 4) {
      #pragma unroll
      for (int h4 = 0; h4 < 4; h4++) {
        const int i_ = k + h4, p = h4, pn = (h4 + 1) & 3;
        const half8 a0 = ldh8(&s0[p][c][q * 8]);
        const half8 a1 = ldh8(&s0[p][c][32 + q * 8]);
        const half8 xf = ldh8(&s0[p][c][64 + q * 8]);
        floatx4 aR = QR, aZ = QZ, a3 = Q3, a4 = Q4;
        {
          floatx4 tR, tZ, tG;
          PASS2_I3(a0, a1, tR, tZ, tG, W1, aR, aZ, a3);  // Whh0.h0 -> gh
          aR = tR; aZ = tZ; a3 = tG;
        }
        PASS1_I1(xf, aR, aZ, a4, W2e, a4);               // Wih0.x  -> gi
        if (doX && i_ + 1 < TSEQ) {
          ((_Float16*)s0[pn])[xo0] = (_Float16)xa0;
          xa0 = xb0;
          if (i_ + 3 < TSEQ) xb0 = px0[(i_ + 3) * NIN];
        }
        NLIN(aR, aZ, a4, a3, &s0[pn][c][ub]);            // nn = tanh(gi_n + gr*gh_n)
        SYNC();
      }
    }
    // ---- tail iteration (k=TSEQ): decoder peel A(0), prev = 0 -> base biases ----
    {
      const half8 a0 = ldh8(&s0[0][c][q * 8]);
      const half8 a1 = ldh8(&s0[0][c][32 + q * 8]);
      floatx4 aR, aZ, a3;
      PASS2_I3(a0, a1, aR, aZ, a3, W1d, TRv, TZv, T3v);
      NLIN(aR, aZ, T4v, a3, &s0[1][c][ub]);
      SYNC();   // bar0: h0_dec(0) visible; B(0) runs in the next window
    }
    // ---- decoder steady: d = 1..179 (i_ = TSEQ+d), 2 barriers per step ----
    for (int i_ = TSEQ + 1; i_ < TSEQ + TDEC; i_++) {
      const int p = i_ & 3, pn = (i_ + 1) & 3;
      // prepass (overlaps B finishing d-1): Whh0d.h0_dec(d-1)
      const half8 a0 = ldh8(&s0[p][c][q * 8]);
      const half8 a1 = ldh8(&s0[p][c][32 + q * 8]);
      floatx4 aR, aZ, a3, a4;
      PASS2_I3(a0, a1, aR, aZ, a3, W1d, DRv, DZv, D3v);
      SYNC();                                          // B(d-1) done -> s1[p] = h1(d-1)
      const half8 b0 = ldh8(&s1[p][c][q * 8]);         // rank-1 head fold: W'.h1(d-1)
      const half8 b1 = ldh8(&s1[p][c][32 + q * 8]);
      PASS2_A2I1(b0, b1, aR, aZ, a4, W2d, D4v);
      NLIN(aR, aZ, a4, a3, &s0[pn][c][ub]);
      SYNC();                                          // A(d) done -> s0[pn]
    }
    SYNC();   // match B's barrier after its last finish (B(179))
  } else {
    // =========================== group B: layer 1 ===========================
    // ============ encoder: iteration kk computes h1_out(kk-1), kk>=1 ============
    for (int k = 0; k < TSEQ; k += 4) {
      #pragma unroll
      for (int h4 = 0; h4 < 4; h4++) {
        const int kk = k + h4;
        if (kk > 0) {
          const int p = (h4 + 3) & 3, pn = h4;         // read s1[(kk-1)&3], s0[kk&3]
          const half8 f0 = ldh8(&s1[p][c][q * 8]);
          const half8 f1 = ldh8(&s1[p][c][32 + q * 8]);
          floatx4 aR, aZ, a3, a4;
          PASS2_I3(f0, f1, aR, aZ, a4, W2, QR, QZ, Q4);  // Whh1.h1 -> gh
          const half8 g0 = ldh8(&s0[pn][c][q * 8]);      // h0_out(kk-1), from prev window
          const half8 g1 = ldh8(&s0[pn][c][32 + q * 8]);
          PASS2_A2I1(g0, g1, aR, aZ, a3, W1, Q3);        // Wih1.h0 -> gi
          NLIN(aR, aZ, a3, a4, &s1[pn][c][ub]);          // nn = tanh(gi_n + gr*gh_n)
        }
        SYNC();
      }
    }
    // ---- tail iteration (kk=TSEQ): encoder step i_=255: s1[3], s0[0] -> s1[0] ----
    {
      const half8 f0 = ldh8(&s1[3][c][q * 8]);
      const half8 f1 = ldh8(&s1[3][c][32 + q * 8]);
      floatx4 aR, aZ, a3, a4;
      PASS2_I3(f0, f1, aR, aZ, a4, W2, QR, QZ, Q4);
      const half8 g0 = ldh8(&s0[0][c][q * 8]);
      const half8 g1 = ldh8(&s0[0][c][32 + q * 8]);
      PASS2_A2I1(g0, g1, aR, aZ, a3, W1, Q3);
      NLIN(aR, aZ, a3, a4, &s1[0][c][ub]);
      SYNC();   // bar0
    }
    // ---- B(0): s1[0] = h1_out(255), s0[1] = h0_dec(0) -> s1[1] = h1_dec(0) ----
    {
      const half8 f0 = ldh8(&s1[0][c][q * 8]);
      const half8 f1 = ldh8(&s1[0][c][32 + q * 8]);
      floatx4 aR, aZ, a3, a4;
      PASS2_I3(f0, f1, aR, aZ, a4, W2d, DRv, DZv, D4v);
      const half8 g0 = ldh8(&s0[1][c][q * 8]);
      const half8 g1 = ldh8(&s0[1][c][32 + q * 8]);
      PASS2_A2I1(g0, g1, aR, aZ, a3, W1d, D3v);
      NLIN(aR, aZ, a3, a4, &s1[1][c][ub]);
      SYNC();   // bar1: h1_dec(0) visible
    }
    // ---- decoder steady: d = 1..179 (i_ = TSEQ+d), 2 barriers per step ----
    for (int i_ = TSEQ + 1; i_ < TSEQ + TDEC; i_++) {
      const int p = i_ & 3, pn = (i_ + 1) & 3;
      // prepass (overlaps A finishing d): Whh1d.h1_dec(d-1), + head cv(d-1)
      const half8 f0 = ldh8(&s1[p][c][q * 8]);
      const half8 f1 = ldh8(&s1[p][c][32 + q * 8]);
      floatx4 aR, aZ, a3, a4;
      PASS2_I3(f0, f1, aR, aZ, a4, W2d, DRv, DZv, D4v);  // Whh1.h1 -> gh
      if (wvL == 0) {   // head: cv(d-1) from h1_dec(d-1) fragments (off critical path)
        float cv = 0.0f;
        #pragma unroll
        for (int j = 0; j < 8; j++) {
          cv = fmaf((float)f0[j], wk[0][j], cv);
          cv = fmaf((float)f1[j], wk[1][j], cv);
        }
        cv += __shfl_xor(cv, 16);
        cv += __shfl_xor(cv, 32);
        if (lane < 16) out[(base + lane) * TDEC + (i_ - TSEQ - 1)] = cv + ob;
      }
      SYNC();                                          // A(d) done -> s0[pn] = h0_dec(d)
      const half8 g0 = ldh8(&s0[pn][c][q * 8]);
      const half8 g1 = ldh8(&s0[pn][c][32 + q * 8]);
      PASS2_A2I1(g0, g1, aR, aZ, a3, W1d, D3v);        // Wih1.h0 -> gi
      NLIN(aR, aZ, a3, a4, &s1[pn][c][ub]);
      SYNC();                                          // B(d) done -> s1[pn]
    }
    // final head value: cv(179) from h1_dec(179) in s1[(436)&3 = 0]
    if (wvL == 0) {
      const half8 f0 = ldh8(&s1[0][c][q * 8]);
      const half8 f1 = ldh8(&s1[0][c][32 + q * 8]);
      float cv = 0.0f;
      #pragma unroll
      for (int j = 0; j < 8; j++) {
        cv = fmaf((float)f0[j], wk[0][j], cv);
        cv = fmaf((float)f1[j], wk[1][j], cv);
      }
      cv += __shfl_xor(cv, 16);
      cv += __shfl_xor(cv, 32);
      if (lane < 16) out[(base + lane) * TDEC + (TDEC - 1)] = cv + ob;
    }
  }
}

extern "C" void kernel_launch(void* const* d_in, const int* in_sizes, int n_in,
                              void* d_out, int out_size, void* d_ws, size_t ws_size,
                              hipStream_t stream) {
  (void)in_sizes; (void)n_in; (void)d_ws; (void)ws_size; (void)out_size;
  const float* x     = (const float*)d_in[0];
  const float* eWih0 = (const float*)d_in[1];
  const float* eWhh0 = (const float*)d_in[2];
  const float* ebih0 = (const float*)d_in[3];
  const float* ebhh0 = (const float*)d_in[4];
  const float* eWih1 = (const float*)d_in[5];
  const float* eWhh1 = (const float*)d_in[6];
  const float* ebih1 = (const float*)d_in[7];
  const float* ebhh1 = (const float*)d_in[8];
  const float* dWih0 = (const float*)d_in[9];
  const float* dWhh0 = (const float*)d_in[10];
  const float* dbih0 = (const float*)d_in[11];
  const float* dbhh0 = (const float*)d_in[12];
  const float* dWih1 = (const float*)d_in[13];
  const float* dWhh1 = (const float*)d_in[14];
  const float* dbih1 = (const float*)d_in[15];
  const float* dbhh1 = (const float*)d_in[16];
  const float* outW  = (const float*)d_in[17];
  const float* outB  = (const float*)d_in[18];
  hipLaunchKernelGGL(gru_persist, dim3(NBLK), dim3(512), 0, stream,
                     x, eWih0, eWhh0, ebih0, ebhh0, eWih1, eWhh1, ebih1, ebhh1,
                     dWih0, dWhh0, dbih0, dbhh0, dWih1, dWhh1, dbih1, dbhh1,
                     outW, outB, (float*)d_out);
}